// Round 1
// baseline (363.546 us; speedup 1.0000x reference)
//
#include <hip/hip_runtime.h>

typedef short short8 __attribute__((ext_vector_type(8)));
typedef float floatx4 __attribute__((ext_vector_type(4)));
typedef unsigned short u16;

#define Tn 2048
#define Kdim 1024

__device__ inline u16 f2bf(float x) {
    union { float f; unsigned u; } c; c.f = x;
    unsigned u = c.u;
    u += 0x7fffu + ((u >> 16) & 1u);   // round-to-nearest-even
    return (u16)(u >> 16);
}
__device__ inline float bf2f(u16 h) {
    union { unsigned u; float f; } c; c.u = ((unsigned)h) << 16;
    return c.f;
}
__device__ inline floatx4 mfma16(short8 a, short8 b, floatx4 c) {
    return __builtin_amdgcn_mfma_f32_16x16x32_bf16(a, b, c, 0, 0, 0);
}
__device__ inline void async16(const void* g, void* l) {
    __builtin_amdgcn_global_load_lds((const __attribute__((address_space(1))) void*)g,
                                     (__attribute__((address_space(3))) void*)l, 16, 0, 0);
}

// ---------------- f32 -> bf16 convert ----------------
__global__ __launch_bounds__(256) void cvt_k(const float* __restrict__ src, u16* __restrict__ dst, int n4) {
    int i = blockIdx.x * 256 + threadIdx.x;
    if (i < n4) {
        float4 v = ((const float4*)src)[i];
        unsigned long long pk = (unsigned long long)f2bf(v.x)
            | ((unsigned long long)f2bf(v.y) << 16)
            | ((unsigned long long)f2bf(v.z) << 32)
            | ((unsigned long long)f2bf(v.w) << 48);
        ((unsigned long long*)dst)[i] = pk;
    }
}

// ---------------- GEMM: C = A(M,K) @ W(N,K)^T + bias, 128x128 tile ----------------
// mode 0: Q (rope, bf16 row-major)   mode 1: K (rope, bf16 row-major)
// mode 2: V -> Vt (B,NH,HS,T) bf16   mode 3: f32 row-major, no bias
__global__ __launch_bounds__(256) void gemm_k(
    const u16* __restrict__ A,
    const u16* __restrict__ W0, const u16* __restrict__ W1, const u16* __restrict__ W2,
    const float* __restrict__ b0, const float* __restrict__ b1, const float* __restrict__ b2,
    void* o0, void* o1, void* o2,
    const float2* __restrict__ rope, int mode_base)
{
    int z = blockIdx.z;
    int mode = mode_base + z;
    const u16* W = (z == 0) ? W0 : (z == 1 ? W1 : W2);
    const float* bias = (z == 0) ? b0 : (z == 1 ? b1 : b2);
    void* outp = (z == 0) ? o0 : (z == 1 ? o1 : o2);

    __shared__ __align__(16) char lds[16384];   // A tile [0,8192), W tile [8192,16384)
    int tid = threadIdx.x;
    int w = tid >> 6, lane = tid & 63, quad = lane >> 4, l15 = lane & 15;
    int m0 = blockIdx.y * 128, n0 = blockIdx.x * 128;
    int wm = (w >> 1) * 64, wn = (w & 1) * 64;

    floatx4 acc[4][4];
    floatx4 vzero = {0.f, 0.f, 0.f, 0.f};
#pragma unroll
    for (int i = 0; i < 4; ++i)
#pragma unroll
        for (int j = 0; j < 4; ++j) acc[i][j] = vzero;

    for (int k0 = 0; k0 < Kdim; k0 += 32) {
        // stage A and W tiles: 128 rows x 32 bf16 each; chunk c of row r placed at
        // slot s = c ^ ((r>>1)&3) (XOR swizzle -> 2-way frag-read conflicts = free)
#pragma unroll
        for (int j = 0; j < 2; ++j) {
            int f = j * 256 + w * 64 + lane;
            int r = f >> 2, s = f & 3;
            int c = s ^ ((r >> 1) & 3);
            const u16* ga = A + (size_t)(m0 + r) * Kdim + k0 + c * 8;
            async16(ga, lds + j * 4096 + w * 1024);
            const u16* gw = W + (size_t)(n0 + r) * Kdim + k0 + c * 8;
            async16(gw, lds + 8192 + j * 4096 + w * 1024);
        }
        __syncthreads();   // drains vmcnt for global_load_lds
        short8 af[4], bfr[4];
#pragma unroll
        for (int mt = 0; mt < 4; ++mt) {
            int ra = wm + mt * 16 + l15;
            af[mt] = *(const short8*)(lds + ra * 64 + ((quad ^ ((ra >> 1) & 3)) << 4));
            int rb = wn + mt * 16 + l15;
            bfr[mt] = *(const short8*)(lds + 8192 + rb * 64 + ((quad ^ ((rb >> 1) & 3)) << 4));
        }
#pragma unroll
        for (int mt = 0; mt < 4; ++mt)
#pragma unroll
            for (int nt = 0; nt < 4; ++nt)
                acc[mt][nt] = mfma16(af[mt], bfr[nt], acc[mt][nt]);
        __syncthreads();
    }

    int mbase = m0 + wm, nbase = n0 + wn;
    if (mode <= 1) {
        // RoPE epilogue: partner col via shfl_xor(1) (C layout: col=lane&15 -> partner=lane^1)
        u16* outb = (u16*)outp;
#pragma unroll
        for (int nt = 0; nt < 4; ++nt) {
            int col = nbase + nt * 16 + l15;
            float bv = bias[col];
            int p = (col & 63) >> 1;
#pragma unroll
            for (int mt = 0; mt < 4; ++mt) {
                floatx4 a = acc[mt][nt];
#pragma unroll
                for (int r = 0; r < 4; ++r) {
                    int row = mbase + mt * 16 + quad * 4 + r;
                    float v = a[r] + bv;
                    float ov = __shfl_xor(v, 1, 64);
                    float2 cs = rope[(row & (Tn - 1)) * 32 + p];
                    float res = cs.x * v + ((lane & 1) ? cs.y * ov : -cs.y * ov);
                    float pres = __shfl_xor(res, 1, 64);
                    if (!(lane & 1)) {
                        unsigned pk = (unsigned)f2bf(res) | ((unsigned)f2bf(pres) << 16);
                        *(unsigned*)(outb + (size_t)row * 1024 + col) = pk;
                    }
                }
            }
        }
    } else if (mode == 2) {
        // V -> Vt[(b*1024+col)*T + t], 4 consecutive t per lane -> 8B store
        u16* vt = (u16*)outp;
#pragma unroll
        for (int nt = 0; nt < 4; ++nt) {
            int col = nbase + nt * 16 + l15;
            float bv = bias[col];
#pragma unroll
            for (int mt = 0; mt < 4; ++mt) {
                floatx4 a = acc[mt][nt];
                int row0 = mbase + mt * 16 + quad * 4;
                int bb = row0 >> 11, t0 = row0 & (Tn - 1);
                unsigned long long pk = (unsigned long long)f2bf(a[0] + bv)
                    | ((unsigned long long)f2bf(a[1] + bv) << 16)
                    | ((unsigned long long)f2bf(a[2] + bv) << 32)
                    | ((unsigned long long)f2bf(a[3] + bv) << 48);
                *(unsigned long long*)(vt + (size_t)(bb * 1024 + col) * Tn + t0) = pk;
            }
        }
    } else {
        float* of = (float*)outp;
#pragma unroll
        for (int nt = 0; nt < 4; ++nt) {
            int col = nbase + nt * 16 + l15;
#pragma unroll
            for (int mt = 0; mt < 4; ++mt) {
                floatx4 a = acc[mt][nt];
#pragma unroll
                for (int r = 0; r < 4; ++r) {
                    int row = mbase + mt * 16 + quad * 4 + r;
                    of[(size_t)row * 1024 + col] = a[r];
                }
            }
        }
    }
}

// ---------------- Vmean (for degenerate fully-masked rows) ----------------
__global__ __launch_bounds__(64) void vmean_k(const u16* __restrict__ Vt, float* __restrict__ vmean) {
    int row = blockIdx.x;
    int lane = threadIdx.x;
    const u16* p = Vt + (size_t)row * Tn;
    float s = 0.f;
    for (int i = lane * 8; i < Tn; i += 512) {
        short8 v = *(const short8*)(p + i);
#pragma unroll
        for (int j = 0; j < 8; ++j) s += bf2f((u16)v[j]);
    }
#pragma unroll
    for (int off = 1; off < 64; off <<= 1) s += __shfl_xor(s, off, 64);
    if (lane == 0) vmean[row] = s * (1.f / 2048.f);
}

// ---------------- Flash attention ----------------
// grid (32 qtiles, 32 b*h), 256 threads; wave w handles 16 queries q0..q0+15.
__global__ __launch_bounds__(256) void flash_k(
    const u16* __restrict__ Qb, const u16* __restrict__ Kb, const u16* __restrict__ Vt,
    const int* __restrict__ masks, const float* __restrict__ vmean, u16* __restrict__ Yb)
{
    int qt = gridDim.x - 1 - blockIdx.x;   // big tiles first (load balance)
    int bh = blockIdx.y;
    int b = bh >> 4, h = bh & 15;
    int tid = threadIdx.x, w = tid >> 6, lane = tid & 63, quad = lane >> 4, l15 = lane & 15;
    int q0 = qt * 64 + w * 16;

    __shared__ __align__(16) u16 ldsK[32 * 72];      // stride 144 B
    __shared__ __align__(16) u16 ldsV[64 * 40];      // Vt tile, stride 80 B
    __shared__ __align__(16) u16 ldsP[4][16 * 40];   // per-wave P, stride 80 B
    __shared__ int smask[32];

    short8 qf[2];
    {
        const u16* qp = Qb + (size_t)(b * Tn + q0 + l15) * 1024 + h * 64 + quad * 8;
        qf[0] = *(const short8*)qp;
        qf[1] = *(const short8*)(qp + 32);
    }
    floatx4 vzero = {0.f, 0.f, 0.f, 0.f};
    floatx4 o[4];
    float m_[4], l_[4];
#pragma unroll
    for (int i = 0; i < 4; ++i) o[i] = vzero;
#pragma unroll
    for (int r = 0; r < 4; ++r) { m_[r] = -1e30f; l_[r] = 0.f; }

    int ktiles = qt * 2 + 2;
    for (int kt = 0; kt < ktiles; ++kt) {
        int k0 = kt * 32;
        __syncthreads();
        {
            int key = tid >> 3, c = tid & 7;
            const u16* kp = Kb + (size_t)(b * Tn + k0 + key) * 1024 + h * 64 + c * 8;
            *(short8*)&ldsK[key * 72 + c * 8] = *(const short8*)kp;
            int d = tid >> 2, c2 = tid & 3;
            const u16* vp = Vt + (size_t)(b * 1024 + h * 64 + d) * Tn + k0 + c2 * 8;
            *(short8*)&ldsV[d * 40 + c2 * 8] = *(const short8*)vp;
            if (tid < 32) smask[tid] = masks[b * Tn + k0 + tid];
        }
        __syncthreads();

        floatx4 s0 = vzero, s1 = vzero;
#pragma unroll
        for (int ks = 0; ks < 2; ++ks) {
            short8 kf0 = *(const short8*)&ldsK[l15 * 72 + ks * 32 + quad * 8];
            short8 kf1 = *(const short8*)&ldsK[(l15 + 16) * 72 + ks * 32 + quad * 8];
            s0 = mfma16(qf[ks], kf0, s0);
            s1 = mfma16(qf[ks], kf1, s1);
        }

        int mk0 = smask[l15], mk1 = smask[16 + l15];
        float p0[4], p1[4], alpha[4];
#pragma unroll
        for (int r = 0; r < 4; ++r) {
            int qq = q0 + quad * 4 + r;
            int key0 = k0 + l15, key1 = k0 + 16 + l15;
            float v0 = (key0 > qq || mk0) ? -1e10f : s0[r] * 0.125f;
            float v1 = (key1 > qq || mk1) ? -1e10f : s1[r] * 0.125f;
            float mx = fmaxf(v0, v1);
#pragma unroll
            for (int off = 1; off < 16; off <<= 1) mx = fmaxf(mx, __shfl_xor(mx, off, 64));
            float mn = fmaxf(m_[r], mx);
            alpha[r] = __expf(m_[r] - mn);
            p0[r] = __expf(v0 - mn);
            p1[r] = __expf(v1 - mn);
            float sm = p0[r] + p1[r];
#pragma unroll
            for (int off = 1; off < 16; off <<= 1) sm += __shfl_xor(sm, off, 64);
            l_[r] = l_[r] * alpha[r] + sm;
            m_[r] = mn;
        }
#pragma unroll
        for (int r = 0; r < 4; ++r) {
            ldsP[w][(quad * 4 + r) * 40 + l15] = f2bf(p0[r]);
            ldsP[w][(quad * 4 + r) * 40 + 16 + l15] = f2bf(p1[r]);
        }
#pragma unroll
        for (int nb = 0; nb < 4; ++nb) {
            floatx4 t = o[nb];
            t[0] *= alpha[0]; t[1] *= alpha[1]; t[2] *= alpha[2]; t[3] *= alpha[3];
            o[nb] = t;
        }
        // wave-internal LDS visibility for the C-layout -> A-layout roundtrip
        __asm__ volatile("s_waitcnt lgkmcnt(0)" ::: "memory");
        short8 pf = *(const short8*)&ldsP[w][l15 * 40 + quad * 8];
#pragma unroll
        for (int nb = 0; nb < 4; ++nb) {
            short8 vf = *(const short8*)&ldsV[(nb * 16 + l15) * 40 + quad * 8];
            o[nb] = mfma16(pf, vf, o[nb]);
        }
    }

#pragma unroll
    for (int r = 0; r < 4; ++r) {
        int qq = q0 + quad * 4 + r;
        float linv = 1.0f / l_[r];
        bool degen = (m_[r] <= -1e9f);   // fully-masked row: reference attends uniformly to ALL T keys
#pragma unroll
        for (int nb = 0; nb < 4; ++nb) {
            int d = nb * 16 + l15;
            float val = degen ? vmean[b * 1024 + h * 64 + d] : o[nb][r] * linv;
            float pv = __shfl_xor(val, 1, 64);
            if (!(lane & 1)) {
                unsigned pk = (unsigned)f2bf(val) | ((unsigned)f2bf(pv) << 16);
                *(unsigned*)(Yb + (size_t)(b * Tn + qq) * 1024 + h * 64 + d) = pk;
            }
        }
    }
}

extern "C" void kernel_launch(void* const* d_in, const int* in_sizes, int n_in,
                              void* d_out, int out_size, void* d_ws, size_t ws_size,
                              hipStream_t stream) {
    const float* x  = (const float*)d_in[0];
    const int* masks = (const int*)d_in[1];
    const float* Wq = (const float*)d_in[2];
    const float* bq = (const float*)d_in[3];
    const float* Wk = (const float*)d_in[4];
    const float* bk = (const float*)d_in[5];
    const float* Wv = (const float*)d_in[6];
    const float* bv = (const float*)d_in[7];
    const float* Wo = (const float*)d_in[8];
    const float2* rope = (const float2*)d_in[9];
    float* out = (float*)d_out;

    char* ws = (char*)d_ws;
    u16* xb   = (u16*)(ws);
    u16* Wqb  = (u16*)(ws + (8  << 20));
    u16* Wkb  = (u16*)(ws + (10 << 20));
    u16* Wvb  = (u16*)(ws + (12 << 20));
    u16* Wob  = (u16*)(ws + (14 << 20));
    u16* Qb   = (u16*)(ws + (16 << 20));
    u16* Kb2  = (u16*)(ws + (24 << 20));
    u16* Vt   = (u16*)(ws + (32 << 20));
    u16* Yb   = (u16*)(ws + (40 << 20));
    float* vm = (float*)(ws + (48 << 20));

    // f32 -> bf16
    cvt_k<<<4096, 256, 0, stream>>>(x,  xb,  1048576);
    cvt_k<<<1024, 256, 0, stream>>>(Wq, Wqb, 262144);
    cvt_k<<<1024, 256, 0, stream>>>(Wk, Wkb, 262144);
    cvt_k<<<1024, 256, 0, stream>>>(Wv, Wvb, 262144);
    cvt_k<<<1024, 256, 0, stream>>>(Wo, Wob, 262144);

    // fused QKV projection (+bias, rope on Q/K, V transposed)
    gemm_k<<<dim3(8, 32, 3), 256, 0, stream>>>(xb, Wqb, Wkb, Wvb, bq, bk, bv,
                                               (void*)Qb, (void*)Kb2, (void*)Vt, rope, 0);
    // mean of V per (b,h,d) for degenerate fully-masked rows
    vmean_k<<<2048, 64, 0, stream>>>(Vt, vm);
    // flash attention
    flash_k<<<dim3(32, 32), 256, 0, stream>>>(Qb, Kb2, Vt, masks, vm, Yb);
    // output projection -> f32 d_out
    gemm_k<<<dim3(8, 32, 1), 256, 0, stream>>>(Yb, Wob, Wob, Wob, nullptr, nullptr, nullptr,
                                               (void*)out, (void*)out, (void*)out, rope, 3);
}

// Round 2
// 262.315 us; speedup vs baseline: 1.3859x; 1.3859x over previous
//
#include <hip/hip_runtime.h>

typedef short short8 __attribute__((ext_vector_type(8)));
typedef float floatx4 __attribute__((ext_vector_type(4)));
typedef unsigned short u16;
typedef unsigned long long u64;

#define Tn 2048
#define Kdim 1024
// 1/sqrt(64) * log2(e): folded into Q so flash softmax runs in exp2 domain
#define QSCALE 0.18033688011112042f

__device__ inline u16 f2bf(float x) {
    union { float f; unsigned u; } c; c.f = x;
    unsigned u = c.u;
    u += 0x7fffu + ((u >> 16) & 1u);   // round-to-nearest-even
    return (u16)(u >> 16);
}
__device__ inline float bf2f(u16 h) {
    union { unsigned u; float f; } c; c.u = ((unsigned)h) << 16;
    return c.f;
}
__device__ inline floatx4 mfma16(short8 a, short8 b, floatx4 c) {
    return __builtin_amdgcn_mfma_f32_16x16x32_bf16(a, b, c, 0, 0, 0);
}
__device__ inline void async16(const void* g, void* l) {
    __builtin_amdgcn_global_load_lds((const __attribute__((address_space(1))) void*)g,
                                     (__attribute__((address_space(3))) void*)l, 16, 0, 0);
}

// ---------------- fused f32 -> bf16 convert (x, Wq, Wk, Wv, Wo) ----------------
// dst regions are contiguous in ws: xb[0,8MB) Wqb[8,10) Wkb[10,12) Wvb[12,14) Wob[14,16)
__global__ __launch_bounds__(256) void cvt_all_k(
    const float* __restrict__ x, const float* __restrict__ wq, const float* __restrict__ wk,
    const float* __restrict__ wv, const float* __restrict__ wo, u16* __restrict__ dst)
{
    int i = blockIdx.x * 256 + threadIdx.x;   // float4 index, 0..2097151
    const float* s; int off;
    if (i < 1048576) { s = x; off = i; }
    else {
        int j = i - 1048576; int seg = j >> 18; off = j & 262143;
        s = (seg == 0) ? wq : (seg == 1) ? wk : (seg == 2) ? wv : wo;
    }
    float4 v = ((const float4*)s)[off];
    u64 pk = (u64)f2bf(v.x) | ((u64)f2bf(v.y) << 16) | ((u64)f2bf(v.z) << 32) | ((u64)f2bf(v.w) << 48);
    ((u64*)dst)[i] = pk;
}

// ---------------- GEMM: C = A(M,K) @ W(N,K)^T + bias, 128x128 tile ----------------
// mode 0: Q (rope + QSCALE, bf16)  mode 1: K (rope, bf16)
// mode 2: V -> Vt (B,NH,HS,T) bf16 mode 3: f32 row-major, no bias
__global__ __launch_bounds__(256) void gemm_k(
    const u16* __restrict__ A,
    const u16* __restrict__ W0, const u16* __restrict__ W1, const u16* __restrict__ W2,
    const float* __restrict__ b0, const float* __restrict__ b1, const float* __restrict__ b2,
    void* o0, void* o1, void* o2,
    const float2* __restrict__ rope, int mode_base)
{
    int z = blockIdx.z;
    int mode = mode_base + z;
    const u16* W = (z == 0) ? W0 : (z == 1 ? W1 : W2);
    const float* bias = (z == 0) ? b0 : (z == 1 ? b1 : b2);
    void* outp = (z == 0) ? o0 : (z == 1 ? o1 : o2);

    __shared__ __align__(16) char lds[16384];
    int tid = threadIdx.x;
    int w = tid >> 6, lane = tid & 63, quad = lane >> 4, l15 = lane & 15;
    int m0 = blockIdx.y * 128, n0 = blockIdx.x * 128;
    int wm = (w >> 1) * 64, wn = (w & 1) * 64;

    floatx4 acc[4][4];
    floatx4 vzero = {0.f, 0.f, 0.f, 0.f};
#pragma unroll
    for (int i = 0; i < 4; ++i)
#pragma unroll
        for (int j = 0; j < 4; ++j) acc[i][j] = vzero;

    for (int k0 = 0; k0 < Kdim; k0 += 32) {
#pragma unroll
        for (int j = 0; j < 2; ++j) {
            int f = j * 256 + w * 64 + lane;
            int r = f >> 2, s = f & 3;
            int c = s ^ ((r >> 1) & 3);
            const u16* ga = A + (size_t)(m0 + r) * Kdim + k0 + c * 8;
            async16(ga, lds + j * 4096 + w * 1024);
            const u16* gw = W + (size_t)(n0 + r) * Kdim + k0 + c * 8;
            async16(gw, lds + 8192 + j * 4096 + w * 1024);
        }
        __syncthreads();
        short8 af[4], bfr[4];
#pragma unroll
        for (int mt = 0; mt < 4; ++mt) {
            int ra = wm + mt * 16 + l15;
            af[mt] = *(const short8*)(lds + ra * 64 + ((quad ^ ((ra >> 1) & 3)) << 4));
            int rb = wn + mt * 16 + l15;
            bfr[mt] = *(const short8*)(lds + 8192 + rb * 64 + ((quad ^ ((rb >> 1) & 3)) << 4));
        }
#pragma unroll
        for (int mt = 0; mt < 4; ++mt)
#pragma unroll
            for (int nt = 0; nt < 4; ++nt)
                acc[mt][nt] = mfma16(af[mt], bfr[nt], acc[mt][nt]);
        __syncthreads();
    }

    int mbase = m0 + wm, nbase = n0 + wn;
    if (mode <= 1) {
        float osc = (mode == 0) ? QSCALE : 1.0f;
        u16* outb = (u16*)outp;
#pragma unroll
        for (int nt = 0; nt < 4; ++nt) {
            int col = nbase + nt * 16 + l15;
            float bv = bias[col];
            int p = (col & 63) >> 1;
#pragma unroll
            for (int mt = 0; mt < 4; ++mt) {
                floatx4 a = acc[mt][nt];
#pragma unroll
                for (int r = 0; r < 4; ++r) {
                    int row = mbase + mt * 16 + quad * 4 + r;
                    float v = a[r] + bv;
                    float ov = __shfl_xor(v, 1, 64);
                    float2 cs = rope[(row & (Tn - 1)) * 32 + p];
                    float res = (cs.x * v + ((lane & 1) ? cs.y * ov : -cs.y * ov)) * osc;
                    float pres = __shfl_xor(res, 1, 64);
                    if (!(lane & 1)) {
                        unsigned pk = (unsigned)f2bf(res) | ((unsigned)f2bf(pres) << 16);
                        *(unsigned*)(outb + (size_t)row * 1024 + col) = pk;
                    }
                }
            }
        }
    } else if (mode == 2) {
        u16* vt = (u16*)outp;
#pragma unroll
        for (int nt = 0; nt < 4; ++nt) {
            int col = nbase + nt * 16 + l15;
            float bv = bias[col];
#pragma unroll
            for (int mt = 0; mt < 4; ++mt) {
                floatx4 a = acc[mt][nt];
                int row0 = mbase + mt * 16 + quad * 4;
                int bb = row0 >> 11, t0 = row0 & (Tn - 1);
                u64 pk = (u64)f2bf(a[0] + bv) | ((u64)f2bf(a[1] + bv) << 16)
                       | ((u64)f2bf(a[2] + bv) << 32) | ((u64)f2bf(a[3] + bv) << 48);
                *(u64*)(vt + (size_t)(bb * 1024 + col) * Tn + t0) = pk;
            }
        }
    } else {
        float* of = (float*)outp;
#pragma unroll
        for (int nt = 0; nt < 4; ++nt) {
            int col = nbase + nt * 16 + l15;
#pragma unroll
            for (int mt = 0; mt < 4; ++mt) {
                floatx4 a = acc[mt][nt];
#pragma unroll
                for (int r = 0; r < 4; ++r) {
                    int row = mbase + mt * 16 + quad * 4 + r;
                    of[(size_t)row * 1024 + col] = a[r];
                }
            }
        }
    }
}

// ---------------- Vmean (for degenerate fully-masked rows) ----------------
__global__ __launch_bounds__(64) void vmean_k(const u16* __restrict__ Vt, float* __restrict__ vmean) {
    int row = blockIdx.x;
    int lane = threadIdx.x;
    const u16* p = Vt + (size_t)row * Tn;
    float s = 0.f;
    for (int i = lane * 8; i < Tn; i += 512) {
        short8 v = *(const short8*)(p + i);
#pragma unroll
        for (int j = 0; j < 8; ++j) s += bf2f((u16)v[j]);
    }
#pragma unroll
    for (int off = 1; off < 64; off <<= 1) s += __shfl_xor(s, off, 64);
    if (lane == 0) vmean[row] = s * (1.f / 2048.f);
}

// ---------------- Flash attention ----------------
// grid (16, 32): block i handles q-tiles {31-i, i} (33 key-tiles each, uniform).
// 64-key tiles, double-buffered async16 staging w/ XOR swizzle, 1 barrier/tile.
__global__ __launch_bounds__(256) void flash_k(
    const u16* __restrict__ Qb, const u16* __restrict__ Kb, const u16* __restrict__ Vt,
    const int* __restrict__ masks, const float* __restrict__ vmean, u16* __restrict__ Yb)
{
    int bh = blockIdx.y;
    int b = bh >> 4, h = bh & 15;
    int tid = threadIdx.x, w = tid >> 6, lane = tid & 63, quad = lane >> 4, l15 = lane & 15;
    int sc = (lane & 7) ^ (lane >> 3);   // staging chunk so that LDS slot = chunk ^ (row&7)

    __shared__ __align__(16) u16 ldsK[2][64 * 64];   // row=key, 8x16B slots, swizzled
    __shared__ __align__(16) u16 ldsV[2][64 * 64];   // row=d,   8x16B slots, swizzled
    __shared__ __align__(16) u16 ldsP[4][16 * 72];   // per wave, row=q, stride 144B

    auto stage = [&](int bb, int k0) {
#pragma unroll
        for (int j = 0; j < 2; ++j) {
            int row = j * 32 + w * 8 + (lane >> 3);
            const u16* gk = Kb + (size_t)(b * Tn + k0 + row) * 1024 + h * 64 + sc * 8;
            async16(gk, (char*)&ldsK[bb][0] + (j * 32 + w * 8) * 128);
            const u16* gv = Vt + (size_t)(b * 1024 + h * 64 + row) * Tn + k0 + sc * 8;
            async16(gv, (char*)&ldsV[bb][0] + (j * 32 + w * 8) * 128);
        }
    };
    floatx4 vzero = {0.f, 0.f, 0.f, 0.f};

    for (int ph = 0; ph < 2; ++ph) {
        int qt = ph ? blockIdx.x : (31 - blockIdx.x);
        int q0 = qt * 64 + w * 16;

        short8 qf[2];
        {
            const u16* qp = Qb + (size_t)(b * Tn + q0 + l15) * 1024 + h * 64 + quad * 8;
            qf[0] = *(const short8*)qp;
            qf[1] = *(const short8*)(qp + 32);
        }
        floatx4 o[4];
        float m_[4], l_[4];
#pragma unroll
        for (int i = 0; i < 4; ++i) o[i] = vzero;
#pragma unroll
        for (int r = 0; r < 4; ++r) { m_[r] = -1e30f; l_[r] = 0.f; }

        int ktiles = qt + 1;
        stage(0, 0);
        for (int kt = 0; kt < ktiles; ++kt) {
            int k0 = kt * 64;
            int bb = kt & 1;
            __syncthreads();   // data for tile kt ready; all waves done with other buffer

            u64 msk = __ballot(masks[b * Tn + k0 + lane] != 0);

            short8 kf[4][2], vf[4][2];
#pragma unroll
            for (int f = 0; f < 4; ++f) {
                int key = f * 16 + l15;
                const char* kbase = (const char*)&ldsK[bb][0] + key * 128;
                const char* vbase = (const char*)&ldsV[bb][0] + key * 128;
#pragma unroll
                for (int ks = 0; ks < 2; ++ks) {
                    int slot = ((quad + ks * 4) ^ (key & 7)) << 4;
                    kf[f][ks] = *(const short8*)(kbase + slot);
                    vf[f][ks] = *(const short8*)(vbase + slot);
                }
            }
            if (kt + 1 < ktiles) stage(bb ^ 1, k0 + 64);   // prefetch flies during compute

            floatx4 s[4];
#pragma unroll
            for (int f = 0; f < 4; ++f) {
                s[f] = mfma16(qf[0], kf[f][0], vzero);
                s[f] = mfma16(qf[1], kf[f][1], s[f]);
            }

            unsigned mlo = (unsigned)msk, mhi = (unsigned)(msk >> 32);
            int mb[4];
            mb[0] = (mlo >> l15) & 1; mb[1] = (mlo >> (l15 + 16)) & 1;
            mb[2] = (mhi >> l15) & 1; mb[3] = (mhi >> (l15 + 16)) & 1;

            float p_[4][4], alpha[4];
#pragma unroll
            for (int r = 0; r < 4; ++r) {
                int lim = q0 + quad * 4 + r - k0;   // key offsets > lim are causal-masked
                float v[4];
#pragma unroll
                for (int f = 0; f < 4; ++f)
                    v[f] = (16 * f + l15 > lim || mb[f]) ? -1e10f : s[f][r];
                float mx = fmaxf(fmaxf(v[0], v[1]), fmaxf(v[2], v[3]));
#pragma unroll
                for (int off = 1; off < 16; off <<= 1) mx = fmaxf(mx, __shfl_xor(mx, off, 64));
                float mn = fmaxf(m_[r], mx);
                alpha[r] = __builtin_amdgcn_exp2f(m_[r] - mn);
                float sm = 0.f;
#pragma unroll
                for (int f = 0; f < 4; ++f) { p_[f][r] = __builtin_amdgcn_exp2f(v[f] - mn); sm += p_[f][r]; }
#pragma unroll
                for (int off = 1; off < 16; off <<= 1) sm += __shfl_xor(sm, off, 64);
                l_[r] = l_[r] * alpha[r] + sm;
                m_[r] = mn;
            }
#pragma unroll
            for (int r = 0; r < 4; ++r)
#pragma unroll
                for (int f = 0; f < 4; ++f) {
                    unsigned u = __float_as_uint(p_[f][r]) + 0x8000u;   // round-half-up bf16
                    ldsP[w][(quad * 4 + r) * 72 + f * 16 + l15] = (u16)(u >> 16);
                }
#pragma unroll
            for (int nb = 0; nb < 4; ++nb) {
                floatx4 t = o[nb];
                t[0] *= alpha[0]; t[1] *= alpha[1]; t[2] *= alpha[2]; t[3] *= alpha[3];
                o[nb] = t;
            }
            __asm__ volatile("s_waitcnt lgkmcnt(0)" ::: "memory");   // wave-local P roundtrip
            short8 pf0 = *(const short8*)((const char*)&ldsP[w][0] + l15 * 144 + quad * 16);
            short8 pf1 = *(const short8*)((const char*)&ldsP[w][0] + l15 * 144 + 64 + quad * 16);
#pragma unroll
            for (int nb = 0; nb < 4; ++nb) {
                o[nb] = mfma16(pf0, vf[nb][0], o[nb]);
                o[nb] = mfma16(pf1, vf[nb][1], o[nb]);
            }
        }
        __syncthreads();   // all waves done with buffers before next phase restages

#pragma unroll
        for (int r = 0; r < 4; ++r) {
            int qq = q0 + quad * 4 + r;
            float linv = 1.0f / l_[r];
            bool degen = (m_[r] <= -1e9f);   // fully-masked row -> uniform attn over ALL keys
#pragma unroll
            for (int nb = 0; nb < 4; ++nb) {
                int d = nb * 16 + l15;
                float val = degen ? vmean[b * 1024 + h * 64 + d] : o[nb][r] * linv;
                float pv = __shfl_xor(val, 1, 64);
                if (!(lane & 1)) {
                    unsigned pk = (unsigned)f2bf(val) | ((unsigned)f2bf(pv) << 16);
                    *(unsigned*)(Yb + (size_t)(b * Tn + qq) * 1024 + h * 64 + d) = pk;
                }
            }
        }
    }
}

extern "C" void kernel_launch(void* const* d_in, const int* in_sizes, int n_in,
                              void* d_out, int out_size, void* d_ws, size_t ws_size,
                              hipStream_t stream) {
    const float* x  = (const float*)d_in[0];
    const int* masks = (const int*)d_in[1];
    const float* Wq = (const float*)d_in[2];
    const float* bq = (const float*)d_in[3];
    const float* Wk = (const float*)d_in[4];
    const float* bk = (const float*)d_in[5];
    const float* Wv = (const float*)d_in[6];
    const float* bv = (const float*)d_in[7];
    const float* Wo = (const float*)d_in[8];
    const float2* rope = (const float2*)d_in[9];
    float* out = (float*)d_out;

    char* ws = (char*)d_ws;
    u16* xb   = (u16*)(ws);
    u16* Wqb  = (u16*)(ws + (8  << 20));
    u16* Wkb  = (u16*)(ws + (10 << 20));
    u16* Wvb  = (u16*)(ws + (12 << 20));
    u16* Wob  = (u16*)(ws + (14 << 20));
    u16* Qb   = (u16*)(ws + (16 << 20));
    u16* Kb2  = (u16*)(ws + (24 << 20));
    u16* Vt   = (u16*)(ws + (32 << 20));
    u16* Yb   = (u16*)(ws + (40 << 20));
    float* vm = (float*)(ws + (48 << 20));

    // fused f32 -> bf16 (x, Wq, Wk, Wv, Wo -> contiguous ws region)
    cvt_all_k<<<8192, 256, 0, stream>>>(x, Wq, Wk, Wv, Wo, xb);

    // fused QKV projection (+bias, rope on Q/K with QSCALE on Q, V transposed)
    gemm_k<<<dim3(8, 32, 3), 256, 0, stream>>>(xb, Wqb, Wkb, Wvb, bq, bk, bv,
                                               (void*)Qb, (void*)Kb2, (void*)Vt, rope, 0);
    // mean of V per (b,h,d) for degenerate fully-masked rows
    vmean_k<<<2048, 64, 0, stream>>>(Vt, vm);
    // flash attention
    flash_k<<<dim3(16, 32), 256, 0, stream>>>(Qb, Kb2, Vt, masks, vm, Yb);
    // output projection -> f32 d_out
    gemm_k<<<dim3(8, 32, 1), 256, 0, stream>>>(Yb, Wob, Wob, Wob, nullptr, nullptr, nullptr,
                                               (void*)out, (void*)out, (void*)out, rope, 3);
}

// Round 3
// 234.386 us; speedup vs baseline: 1.5511x; 1.1192x over previous
//
#include <hip/hip_runtime.h>

typedef short short8 __attribute__((ext_vector_type(8)));
typedef float floatx4 __attribute__((ext_vector_type(4)));
typedef unsigned short u16;
typedef unsigned long long u64;

#define Tn 2048
#define Kdim 1024
// 1/sqrt(64) * log2(e): folded into Q so flash softmax runs in exp2 domain
#define QSCALE 0.18033688011112042f
#define FIXEDMAX 20.0f   // exp2-domain logits are ~+-5; 20 is a safe fixed max

__device__ inline u16 f2bf(float x) {
    union { float f; unsigned u; } c; c.f = x;
    unsigned u = c.u;
    u += 0x7fffu + ((u >> 16) & 1u);   // round-to-nearest-even
    return (u16)(u >> 16);
}
__device__ inline float bf2f(u16 h) {
    union { unsigned u; float f; } c; c.u = ((unsigned)h) << 16;
    return c.f;
}
__device__ inline floatx4 mfma16(short8 a, short8 b, floatx4 c) {
    return __builtin_amdgcn_mfma_f32_16x16x32_bf16(a, b, c, 0, 0, 0);
}
__device__ inline void async16(const void* g, void* l) {
    __builtin_amdgcn_global_load_lds((const __attribute__((address_space(1))) void*)g,
                                     (__attribute__((address_space(3))) void*)l, 16, 0, 0);
}

// ---------------- fused f32 -> bf16 convert (x, Wq, Wk, Wv, Wo) ----------------
__global__ __launch_bounds__(256) void cvt_all_k(
    const float* __restrict__ x, const float* __restrict__ wq, const float* __restrict__ wk,
    const float* __restrict__ wv, const float* __restrict__ wo, u16* __restrict__ dst)
{
    int i = blockIdx.x * 256 + threadIdx.x;   // float4 index
    const float* s; int off;
    if (i < 1048576) { s = x; off = i; }
    else {
        int j = i - 1048576; int seg = j >> 18; off = j & 262143;
        s = (seg == 0) ? wq : (seg == 1) ? wk : (seg == 2) ? wv : wo;
    }
    float4 v = ((const float4*)s)[off];
    u64 pk = (u64)f2bf(v.x) | ((u64)f2bf(v.y) << 16) | ((u64)f2bf(v.z) << 32) | ((u64)f2bf(v.w) << 48);
    ((u64*)dst)[i] = pk;
}

// ---------------- GEMM: C = A(M,K) @ W(N,K)^T + bias, 128x128 tile, BK=64 ----------------
// mode 0: Q (rope + QSCALE, bf16)  mode 1: K (rope, bf16)
// mode 2: V -> Vt (B,NH,HS,T) bf16 mode 3: f32 row-major, no bias
__global__ __launch_bounds__(256) void gemm_k(
    const u16* __restrict__ A,
    const u16* __restrict__ W0, const u16* __restrict__ W1, const u16* __restrict__ W2,
    const float* __restrict__ b0, const float* __restrict__ b1, const float* __restrict__ b2,
    void* o0, void* o1, void* o2,
    const float2* __restrict__ rope, int mode_base)
{
    int z = blockIdx.z;
    int mode = mode_base + z;
    const u16* W = (z == 0) ? W0 : (z == 1 ? W1 : W2);
    const float* bias = (z == 0) ? b0 : (z == 1 ? b1 : b2);
    void* outp = (z == 0) ? o0 : (z == 1 ? o1 : o2);

    __shared__ __align__(16) char lds[32768];   // A [0,16K), W [16K,32K); rows 128B, 8 slots, XOR-swizzled
    int tid = threadIdx.x;
    int w = tid >> 6, lane = tid & 63, quad = lane >> 4, l15 = lane & 15;
    int m0 = blockIdx.y * 128, n0 = blockIdx.x * 128;
    int wm = (w >> 1) * 64, wn = (w & 1) * 64;
    int row8 = tid >> 3, c8 = tid & 7;

    floatx4 acc[4][4];
    floatx4 vzero = {0.f, 0.f, 0.f, 0.f};
#pragma unroll
    for (int i = 0; i < 4; ++i)
#pragma unroll
        for (int j = 0; j < 4; ++j) acc[i][j] = vzero;

    for (int k0 = 0; k0 < Kdim; k0 += 64) {
#pragma unroll
        for (int j = 0; j < 4; ++j) {
            int r = j * 32 + row8;
            int ca = c8 ^ (r & 7);
            async16(A + (size_t)(m0 + r) * Kdim + k0 + ca * 8, lds + j * 4096 + w * 1024);
            async16(W + (size_t)(n0 + r) * Kdim + k0 + ca * 8, lds + 16384 + j * 4096 + w * 1024);
        }
        __syncthreads();
        short8 af[4][2], bfr[4][2];
#pragma unroll
        for (int mt = 0; mt < 4; ++mt) {
            int ra = wm + mt * 16 + l15;
            int rb = wn + mt * 16 + l15;
            const char* pa = lds + ra * 128;
            const char* pb = lds + 16384 + rb * 128;
#pragma unroll
            for (int ks = 0; ks < 2; ++ks) {
                af[mt][ks]  = *(const short8*)(pa + (((ks * 4 + quad) ^ (ra & 7)) << 4));
                bfr[mt][ks] = *(const short8*)(pb + (((ks * 4 + quad) ^ (rb & 7)) << 4));
            }
        }
#pragma unroll
        for (int ks = 0; ks < 2; ++ks)
#pragma unroll
            for (int mt = 0; mt < 4; ++mt)
#pragma unroll
                for (int nt = 0; nt < 4; ++nt)
                    acc[mt][nt] = mfma16(af[mt][ks], bfr[nt][ks], acc[mt][nt]);
        __syncthreads();
    }

    int mbase = m0 + wm, nbase = n0 + wn;
    if (mode <= 1) {
        float osc = (mode == 0) ? QSCALE : 1.0f;
        u16* outb = (u16*)outp;
#pragma unroll
        for (int nt = 0; nt < 4; ++nt) {
            int col = nbase + nt * 16 + l15;
            float bv = bias[col];
            int p = (col & 63) >> 1;
#pragma unroll
            for (int mt = 0; mt < 4; ++mt) {
                floatx4 a = acc[mt][nt];
#pragma unroll
                for (int r = 0; r < 4; ++r) {
                    int row = mbase + mt * 16 + quad * 4 + r;
                    float v = a[r] + bv;
                    float ov = __shfl_xor(v, 1, 64);
                    float2 cs = rope[(row & (Tn - 1)) * 32 + p];
                    float res = (cs.x * v + ((lane & 1) ? cs.y * ov : -cs.y * ov)) * osc;
                    float pres = __shfl_xor(res, 1, 64);
                    if (!(lane & 1)) {
                        unsigned pk = (unsigned)f2bf(res) | ((unsigned)f2bf(pres) << 16);
                        *(unsigned*)(outb + (size_t)row * 1024 + col) = pk;
                    }
                }
            }
        }
    } else if (mode == 2) {
        u16* vt = (u16*)outp;
#pragma unroll
        for (int nt = 0; nt < 4; ++nt) {
            int col = nbase + nt * 16 + l15;
            float bv = bias[col];
#pragma unroll
            for (int mt = 0; mt < 4; ++mt) {
                floatx4 a = acc[mt][nt];
                int row0 = mbase + mt * 16 + quad * 4;
                int bb = row0 >> 11, t0 = row0 & (Tn - 1);
                u64 pk = (u64)f2bf(a[0] + bv) | ((u64)f2bf(a[1] + bv) << 16)
                       | ((u64)f2bf(a[2] + bv) << 32) | ((u64)f2bf(a[3] + bv) << 48);
                *(u64*)(vt + (size_t)(bb * 1024 + col) * Tn + t0) = pk;
            }
        }
    } else {
        float* of = (float*)outp;
#pragma unroll
        for (int nt = 0; nt < 4; ++nt) {
            int col = nbase + nt * 16 + l15;
#pragma unroll
            for (int mt = 0; mt < 4; ++mt) {
                floatx4 a = acc[mt][nt];
#pragma unroll
                for (int r = 0; r < 4; ++r) {
                    int row = mbase + mt * 16 + quad * 4 + r;
                    of[(size_t)row * 1024 + col] = a[r];
                }
            }
        }
    }
}

// ---------------- Vmean (for degenerate fully-masked rows) ----------------
__global__ __launch_bounds__(64) void vmean_k(const u16* __restrict__ Vt, float* __restrict__ vmean) {
    int row = blockIdx.x;
    int lane = threadIdx.x;
    const u16* p = Vt + (size_t)row * Tn;
    float s = 0.f;
    for (int i = lane * 8; i < Tn; i += 512) {
        short8 v = *(const short8*)(p + i);
#pragma unroll
        for (int j = 0; j < 8; ++j) s += bf2f((u16)v[j]);
    }
#pragma unroll
    for (int off = 1; off < 64; off <<= 1) s += __shfl_xor(s, off, 64);
    if (lane == 0) vmean[row] = s * (1.f / 2048.f);
}

// ---------------- Flash attention (fixed-max exp2 softmax) ----------------
// grid (16, 32): block i handles q-tiles {31-i, i} (33 key-tiles each, uniform).
// 64-key tiles, double-buffered async16 staging w/ XOR swizzle, 1 barrier/tile.
// No running max / no per-tile reductions: p = exp2(v - FIXEDMAX); l reduced once per q-tile.
__global__ __launch_bounds__(256) void flash_k(
    const u16* __restrict__ Qb, const u16* __restrict__ Kb, const u16* __restrict__ Vt,
    const int* __restrict__ masks, const float* __restrict__ vmean, u16* __restrict__ Yb)
{
    int bh = blockIdx.y;
    int b = bh >> 4, h = bh & 15;
    int tid = threadIdx.x, w = tid >> 6, lane = tid & 63, quad = lane >> 4, l15 = lane & 15;
    int sc = (lane & 7) ^ (lane >> 3);   // staging chunk so that LDS slot = chunk ^ (row&7)

    __shared__ __align__(16) u16 ldsK[2][64 * 64];   // row=key, 8x16B slots, swizzled
    __shared__ __align__(16) u16 ldsV[2][64 * 64];   // row=d,   8x16B slots, swizzled
    __shared__ __align__(16) u16 ldsP[4][16 * 72];   // per wave, row=q, stride 144B
    __shared__ u64 smsk[32];                         // mask ballot per 64-key tile

    // all 32 mask ballots once per block (wave w covers tiles 8w..8w+7)
#pragma unroll
    for (int j = 0; j < 8; ++j) {
        u64 mk = __ballot(masks[b * Tn + (w * 8 + j) * 64 + lane] != 0);
        if (lane == 0) smsk[w * 8 + j] = mk;
    }

    auto stage = [&](int bb, int k0) {
#pragma unroll
        for (int j = 0; j < 2; ++j) {
            int row = j * 32 + w * 8 + (lane >> 3);
            const u16* gk = Kb + (size_t)(b * Tn + k0 + row) * 1024 + h * 64 + sc * 8;
            async16(gk, (char*)&ldsK[bb][0] + (j * 32 + w * 8) * 128);
            const u16* gv = Vt + (size_t)(b * 1024 + h * 64 + row) * Tn + k0 + sc * 8;
            async16(gv, (char*)&ldsV[bb][0] + (j * 32 + w * 8) * 128);
        }
    };
    floatx4 vzero = {0.f, 0.f, 0.f, 0.f};

    for (int ph = 0; ph < 2; ++ph) {
        int qt = ph ? blockIdx.x : (31 - blockIdx.x);
        int q0 = qt * 64 + w * 16;

        short8 qf[2];
        {
            const u16* qp = Qb + (size_t)(b * Tn + q0 + l15) * 1024 + h * 64 + quad * 8;
            qf[0] = *(const short8*)qp;
            qf[1] = *(const short8*)(qp + 32);
        }
        floatx4 o[4];
        float lsum[4] = {0.f, 0.f, 0.f, 0.f};
#pragma unroll
        for (int i = 0; i < 4; ++i) o[i] = vzero;

        int ktiles = qt + 1;
        stage(0, 0);
        for (int kt = 0; kt < ktiles; ++kt) {
            int k0 = kt * 64;
            int bb = kt & 1;
            __syncthreads();   // tile kt staged; all waves done with other buffer

            short8 kf[4][2], vf[4][2];
#pragma unroll
            for (int f = 0; f < 4; ++f) {
                int key = f * 16 + l15;
                const char* kbase = (const char*)&ldsK[bb][0] + key * 128;
                const char* vbase = (const char*)&ldsV[bb][0] + key * 128;
#pragma unroll
                for (int ks = 0; ks < 2; ++ks) {
                    int slot = ((quad + ks * 4) ^ (key & 7)) << 4;
                    kf[f][ks] = *(const short8*)(kbase + slot);
                    vf[f][ks] = *(const short8*)(vbase + slot);
                }
            }
            if (kt + 1 < ktiles) stage(bb ^ 1, k0 + 64);   // prefetch flies during compute

            floatx4 s[4];
#pragma unroll
            for (int f = 0; f < 4; ++f) {
                s[f] = mfma16(qf[0], kf[f][0], vzero);
                s[f] = mfma16(qf[1], kf[f][1], s[f]);
            }

            u64 msk = smsk[kt];
            unsigned mlo = (unsigned)msk, mhi = (unsigned)(msk >> 32);
            int mb[4];
            mb[0] = (mlo >> l15) & 1; mb[1] = (mlo >> (l15 + 16)) & 1;
            mb[2] = (mhi >> l15) & 1; mb[3] = (mhi >> (l15 + 16)) & 1;

#pragma unroll
            for (int r = 0; r < 4; ++r) {
                int lim = q0 + quad * 4 + r - k0;   // key offsets > lim are causal-masked
                float psum = 0.f;
#pragma unroll
                for (int f = 0; f < 4; ++f) {
                    float v = (16 * f + l15 > lim || mb[f]) ? -1e10f : s[f][r];
                    float p = __builtin_amdgcn_exp2f(v - FIXEDMAX);
                    psum += p;
                    unsigned u = __float_as_uint(p) + 0x8000u;   // round-half-up bf16
                    ldsP[w][(quad * 4 + r) * 72 + f * 16 + l15] = (u16)(u >> 16);
                }
                lsum[r] += psum;
            }
            __asm__ volatile("s_waitcnt lgkmcnt(0)" ::: "memory");   // wave-local P roundtrip
            short8 pf0 = *(const short8*)((const char*)&ldsP[w][0] + l15 * 144 + quad * 16);
            short8 pf1 = *(const short8*)((const char*)&ldsP[w][0] + l15 * 144 + 64 + quad * 16);
#pragma unroll
            for (int nb = 0; nb < 4; ++nb) {
                o[nb] = mfma16(pf0, vf[nb][0], o[nb]);
                o[nb] = mfma16(pf1, vf[nb][1], o[nb]);
            }
        }
        __syncthreads();   // all waves done with buffers before next phase restages

#pragma unroll
        for (int r = 0; r < 4; ++r) {
            int qq = q0 + quad * 4 + r;
            float l = lsum[r];
#pragma unroll
            for (int off = 1; off < 16; off <<= 1) l += __shfl_xor(l, off, 64);
            bool degen = (l == 0.f);   // fully-masked row -> reference attends uniformly to ALL keys
            float linv = 1.0f / l;
#pragma unroll
            for (int nb = 0; nb < 4; ++nb) {
                int d = nb * 16 + l15;
                float val = degen ? vmean[b * 1024 + h * 64 + d] : o[nb][r] * linv;
                float pv = __shfl_xor(val, 1, 64);
                if (!(lane & 1)) {
                    unsigned pk = (unsigned)f2bf(val) | ((unsigned)f2bf(pv) << 16);
                    *(unsigned*)(Yb + (size_t)(b * Tn + qq) * 1024 + h * 64 + d) = pk;
                }
            }
        }
    }
}

extern "C" void kernel_launch(void* const* d_in, const int* in_sizes, int n_in,
                              void* d_out, int out_size, void* d_ws, size_t ws_size,
                              hipStream_t stream) {
    const float* x  = (const float*)d_in[0];
    const int* masks = (const int*)d_in[1];
    const float* Wq = (const float*)d_in[2];
    const float* bq = (const float*)d_in[3];
    const float* Wk = (const float*)d_in[4];
    const float* bk = (const float*)d_in[5];
    const float* Wv = (const float*)d_in[6];
    const float* bv = (const float*)d_in[7];
    const float* Wo = (const float*)d_in[8];
    const float2* rope = (const float2*)d_in[9];
    float* out = (float*)d_out;

    char* ws = (char*)d_ws;
    u16* xb   = (u16*)(ws);
    u16* Wqb  = (u16*)(ws + (8  << 20));
    u16* Wkb  = (u16*)(ws + (10 << 20));
    u16* Wvb  = (u16*)(ws + (12 << 20));
    u16* Wob  = (u16*)(ws + (14 << 20));
    u16* Qb   = (u16*)(ws + (16 << 20));
    u16* Kb2  = (u16*)(ws + (24 << 20));
    u16* Vt   = (u16*)(ws + (32 << 20));
    u16* Yb   = (u16*)(ws + (40 << 20));
    float* vm = (float*)(ws + (48 << 20));

    // fused f32 -> bf16 (x, Wq, Wk, Wv, Wo -> contiguous ws region)
    cvt_all_k<<<8192, 256, 0, stream>>>(x, Wq, Wk, Wv, Wo, xb);

    // fused QKV projection (+bias, rope on Q/K with QSCALE on Q, V transposed)
    gemm_k<<<dim3(8, 32, 3), 256, 0, stream>>>(xb, Wqb, Wkb, Wvb, bq, bk, bv,
                                               (void*)Qb, (void*)Kb2, (void*)Vt, rope, 0);
    // mean of V per (b,h,d) for degenerate fully-masked rows
    vmean_k<<<2048, 64, 0, stream>>>(Vt, vm);
    // flash attention
    flash_k<<<dim3(16, 32), 256, 0, stream>>>(Qb, Kb2, Vt, masks, vm, Yb);
    // output projection -> f32 d_out
    gemm_k<<<dim3(8, 32, 1), 256, 0, stream>>>(Yb, Wob, Wob, Wob, nullptr, nullptr, nullptr,
                                               (void*)out, (void*)out, (void*)out, rope, 3);
}

// Round 4
// 202.265 us; speedup vs baseline: 1.7974x; 1.1588x over previous
//
#include <hip/hip_runtime.h>

typedef short short8 __attribute__((ext_vector_type(8)));
typedef float floatx4 __attribute__((ext_vector_type(4)));
typedef unsigned short u16;
typedef unsigned long long u64;

#define Tn 2048
#define Kdim 1024
// 1/sqrt(64) * log2(e): folded into Q so flash softmax runs in exp2 domain
#define QSCALE 0.18033688011112042f
#define FIXEDMAX 20.0f   // exp2-domain logits are ~+-5; 20 is a safe fixed max

__device__ inline u16 f2bf(float x) {
    union { float f; unsigned u; } c; c.f = x;
    unsigned u = c.u;
    u += 0x7fffu + ((u >> 16) & 1u);   // round-to-nearest-even
    return (u16)(u >> 16);
}
__device__ inline float bf2f(u16 h) {
    union { unsigned u; float f; } c; c.u = ((unsigned)h) << 16;
    return c.f;
}
__device__ inline floatx4 mfma16(short8 a, short8 b, floatx4 c) {
    return __builtin_amdgcn_mfma_f32_16x16x32_bf16(a, b, c, 0, 0, 0);
}
__device__ inline void async16(const void* g, void* l) {
    __builtin_amdgcn_global_load_lds((const __attribute__((address_space(1))) void*)g,
                                     (__attribute__((address_space(3))) void*)l, 16, 0, 0);
}

// ---------------- fused f32 -> bf16 convert (x, Wq, Wk, Wv, Wo) ----------------
__global__ __launch_bounds__(256) void cvt_all_k(
    const float* __restrict__ x, const float* __restrict__ wq, const float* __restrict__ wk,
    const float* __restrict__ wv, const float* __restrict__ wo, u16* __restrict__ dst)
{
    int i = blockIdx.x * 256 + threadIdx.x;   // float4 index
    const float* s; int off;
    if (i < 1048576) { s = x; off = i; }
    else {
        int j = i - 1048576; int seg = j >> 18; off = j & 262143;
        s = (seg == 0) ? wq : (seg == 1) ? wk : (seg == 2) ? wv : wo;
    }
    float4 v = ((const float4*)s)[off];
    u64 pk = (u64)f2bf(v.x) | ((u64)f2bf(v.y) << 16) | ((u64)f2bf(v.z) << 32) | ((u64)f2bf(v.w) << 48);
    ((u64*)dst)[i] = pk;
}

// ---------------- QKV GEMM: C = A(M,K) @ W(N,K)^T + bias, 128M x 64N tile, BK=64 ----------------
// 256 threads, wave-tile 32M x 64N (acc 2x4). Grid (16, 32, 3) = 1536 blocks -> 5 blocks/CU.
// mode 0: Q (rope + QSCALE, bf16)  mode 1: K (rope, bf16)  mode 2: V -> Vt (B,NH,HS,T) bf16
__global__ __launch_bounds__(256, 5) void gemm_qkv_k(
    const u16* __restrict__ A,
    const u16* __restrict__ W0, const u16* __restrict__ W1, const u16* __restrict__ W2,
    const float* __restrict__ b0, const float* __restrict__ b1, const float* __restrict__ b2,
    u16* o0, u16* o1, u16* o2,
    const float2* __restrict__ rope)
{
    int z = blockIdx.z;
    const u16* W = (z == 0) ? W0 : (z == 1 ? W1 : W2);
    const float* bias = (z == 0) ? b0 : (z == 1 ? b1 : b2);
    u16* outp = (z == 0) ? o0 : (z == 1 ? o1 : o2);

    __shared__ __align__(16) char lds[24576];   // A [0,16K): 128 rows x 128B; W [16K,24K): 64 rows x 128B
    int tid = threadIdx.x;
    int w = tid >> 6, lane = tid & 63, quad = lane >> 4, l15 = lane & 15;
    int m0 = blockIdx.y * 128, n0 = blockIdx.x * 64;
    int wm = w * 32;

    floatx4 acc[2][4];
    floatx4 vzero = {0.f, 0.f, 0.f, 0.f};
#pragma unroll
    for (int i = 0; i < 2; ++i)
#pragma unroll
        for (int j = 0; j < 4; ++j) acc[i][j] = vzero;

    for (int k0 = 0; k0 < Kdim; k0 += 64) {
        // stage A (128x64, 4 per thread) + W (64x64, 2 per thread), XOR chunk swizzle
#pragma unroll
        for (int j = 0; j < 4; ++j) {
            int f = j * 256 + tid, r = f >> 3, c = (f & 7) ^ (r & 7);
            async16(A + (size_t)(m0 + r) * Kdim + k0 + c * 8, lds + j * 4096 + w * 1024);
        }
#pragma unroll
        for (int j = 0; j < 2; ++j) {
            int f = j * 256 + tid, r = f >> 3, c = (f & 7) ^ (r & 7);
            async16(W + (size_t)(n0 + r) * Kdim + k0 + c * 8, lds + 16384 + j * 4096 + w * 1024);
        }
        __syncthreads();
        short8 af[2][2];
#pragma unroll
        for (int mt = 0; mt < 2; ++mt) {
            int ra = wm + mt * 16 + l15;
            const char* pa = lds + ra * 128;
#pragma unroll
            for (int ks = 0; ks < 2; ++ks)
                af[mt][ks] = *(const short8*)(pa + (((ks * 4 + quad) ^ (ra & 7)) << 4));
        }
#pragma unroll
        for (int ks = 0; ks < 2; ++ks)
#pragma unroll
            for (int nt = 0; nt < 4; ++nt) {
                int rb = nt * 16 + l15;
                short8 bf = *(const short8*)(lds + 16384 + rb * 128 + (((ks * 4 + quad) ^ (rb & 7)) << 4));
                acc[0][nt] = mfma16(af[0][ks], bf, acc[0][nt]);
                acc[1][nt] = mfma16(af[1][ks], bf, acc[1][nt]);
            }
        __syncthreads();
    }

    int mbase = m0 + wm;
    if (z <= 1) {
        float osc = (z == 0) ? QSCALE : 1.0f;
#pragma unroll
        for (int nt = 0; nt < 4; ++nt) {
            int col = n0 + nt * 16 + l15;
            float bv = bias[col];
            int p = (col & 63) >> 1;
#pragma unroll
            for (int mt = 0; mt < 2; ++mt) {
                floatx4 a = acc[mt][nt];
#pragma unroll
                for (int r = 0; r < 4; ++r) {
                    int row = mbase + mt * 16 + quad * 4 + r;
                    float v = a[r] + bv;
                    float ov = __shfl_xor(v, 1, 64);
                    float2 cs = rope[(row & (Tn - 1)) * 32 + p];
                    float res = (cs.x * v + ((lane & 1) ? cs.y * ov : -cs.y * ov)) * osc;
                    float pres = __shfl_xor(res, 1, 64);
                    if (!(lane & 1)) {
                        unsigned pk = (unsigned)f2bf(res) | ((unsigned)f2bf(pres) << 16);
                        *(unsigned*)(outp + (size_t)row * 1024 + col) = pk;
                    }
                }
            }
        }
    } else {
        // V -> Vt[(b*1024+col)*T + t]
#pragma unroll
        for (int nt = 0; nt < 4; ++nt) {
            int col = n0 + nt * 16 + l15;
            float bv = bias[col];
#pragma unroll
            for (int mt = 0; mt < 2; ++mt) {
                floatx4 a = acc[mt][nt];
                int row0 = mbase + mt * 16 + quad * 4;
                int bb = row0 >> 11, t0 = row0 & (Tn - 1);
                u64 pk = (u64)f2bf(a[0] + bv) | ((u64)f2bf(a[1] + bv) << 16)
                       | ((u64)f2bf(a[2] + bv) << 32) | ((u64)f2bf(a[3] + bv) << 48);
                *(u64*)(outp + (size_t)(bb * 1024 + col) * Tn + t0) = pk;
            }
        }
    }
}

// ---------------- O-projection GEMM: out = Y(M,K) @ Wo(N,K)^T, f32 out, 64x64 tile ----------------
// 256 threads, wave-tile 32x32 (acc 2x2). Grid (16, 64) = 1024 blocks -> 4 blocks/CU, uniform.
__global__ __launch_bounds__(256, 4) void gemm_o_k(
    const u16* __restrict__ A, const u16* __restrict__ W, float* __restrict__ out)
{
    __shared__ __align__(16) char lds[16384];   // A [0,8K): 64 rows x 128B; W [8K,16K)
    int tid = threadIdx.x;
    int w = tid >> 6, lane = tid & 63, quad = lane >> 4, l15 = lane & 15;
    int m0 = blockIdx.y * 64, n0 = blockIdx.x * 64;
    int wm = (w >> 1) * 32, wn = (w & 1) * 32;

    floatx4 acc[2][2];
    floatx4 vzero = {0.f, 0.f, 0.f, 0.f};
#pragma unroll
    for (int i = 0; i < 2; ++i)
#pragma unroll
        for (int j = 0; j < 2; ++j) acc[i][j] = vzero;

    for (int k0 = 0; k0 < Kdim; k0 += 64) {
#pragma unroll
        for (int j = 0; j < 2; ++j) {
            int f = j * 256 + tid, r = f >> 3, c = (f & 7) ^ (r & 7);
            async16(A + (size_t)(m0 + r) * Kdim + k0 + c * 8, lds + j * 4096 + w * 1024);
            async16(W + (size_t)(n0 + r) * Kdim + k0 + c * 8, lds + 8192 + j * 4096 + w * 1024);
        }
        __syncthreads();
        short8 af[2][2];
#pragma unroll
        for (int mt = 0; mt < 2; ++mt) {
            int ra = wm + mt * 16 + l15;
            const char* pa = lds + ra * 128;
#pragma unroll
            for (int ks = 0; ks < 2; ++ks)
                af[mt][ks] = *(const short8*)(pa + (((ks * 4 + quad) ^ (ra & 7)) << 4));
        }
#pragma unroll
        for (int ks = 0; ks < 2; ++ks)
#pragma unroll
            for (int nt = 0; nt < 2; ++nt) {
                int rb = wn + nt * 16 + l15;
                short8 bf = *(const short8*)(lds + 8192 + rb * 128 + (((ks * 4 + quad) ^ (rb & 7)) << 4));
                acc[0][nt] = mfma16(af[0][ks], bf, acc[0][nt]);
                acc[1][nt] = mfma16(af[1][ks], bf, acc[1][nt]);
            }
        __syncthreads();
    }

#pragma unroll
    for (int nt = 0; nt < 2; ++nt) {
        int col = n0 + wn + nt * 16 + l15;
#pragma unroll
        for (int mt = 0; mt < 2; ++mt) {
            floatx4 a = acc[mt][nt];
#pragma unroll
            for (int r = 0; r < 4; ++r) {
                int row = m0 + wm + mt * 16 + quad * 4 + r;
                out[(size_t)row * 1024 + col] = a[r];
            }
        }
    }
}

// ---------------- Vmean (for degenerate fully-masked rows) ----------------
__global__ __launch_bounds__(64) void vmean_k(const u16* __restrict__ Vt, float* __restrict__ vmean) {
    int row = blockIdx.x;
    int lane = threadIdx.x;
    const u16* p = Vt + (size_t)row * Tn;
    float s = 0.f;
    for (int i = lane * 8; i < Tn; i += 512) {
        short8 v = *(const short8*)(p + i);
#pragma unroll
        for (int j = 0; j < 8; ++j) s += bf2f((u16)v[j]);
    }
#pragma unroll
    for (int off = 1; off < 64; off <<= 1) s += __shfl_xor(s, off, 64);
    if (lane == 0) vmean[row] = s * (1.f / 2048.f);
}

// ---------------- Flash attention (fixed-max exp2 softmax) ----------------
__global__ __launch_bounds__(256) void flash_k(
    const u16* __restrict__ Qb, const u16* __restrict__ Kb, const u16* __restrict__ Vt,
    const int* __restrict__ masks, const float* __restrict__ vmean, u16* __restrict__ Yb)
{
    int bh = blockIdx.y;
    int b = bh >> 4, h = bh & 15;
    int tid = threadIdx.x, w = tid >> 6, lane = tid & 63, quad = lane >> 4, l15 = lane & 15;
    int sc = (lane & 7) ^ (lane >> 3);   // staging chunk so that LDS slot = chunk ^ (row&7)

    __shared__ __align__(16) u16 ldsK[2][64 * 64];   // row=key, 8x16B slots, swizzled
    __shared__ __align__(16) u16 ldsV[2][64 * 64];   // row=d,   8x16B slots, swizzled
    __shared__ __align__(16) u16 ldsP[4][16 * 72];   // per wave, row=q, stride 144B
    __shared__ u64 smsk[32];                         // mask ballot per 64-key tile

#pragma unroll
    for (int j = 0; j < 8; ++j) {
        u64 mk = __ballot(masks[b * Tn + (w * 8 + j) * 64 + lane] != 0);
        if (lane == 0) smsk[w * 8 + j] = mk;
    }

    auto stage = [&](int bb, int k0) {
#pragma unroll
        for (int j = 0; j < 2; ++j) {
            int row = j * 32 + w * 8 + (lane >> 3);
            const u16* gk = Kb + (size_t)(b * Tn + k0 + row) * 1024 + h * 64 + sc * 8;
            async16(gk, (char*)&ldsK[bb][0] + (j * 32 + w * 8) * 128);
            const u16* gv = Vt + (size_t)(b * 1024 + h * 64 + row) * Tn + k0 + sc * 8;
            async16(gv, (char*)&ldsV[bb][0] + (j * 32 + w * 8) * 128);
        }
    };
    floatx4 vzero = {0.f, 0.f, 0.f, 0.f};

    for (int ph = 0; ph < 2; ++ph) {
        int qt = ph ? blockIdx.x : (31 - blockIdx.x);
        int q0 = qt * 64 + w * 16;

        short8 qf[2];
        {
            const u16* qp = Qb + (size_t)(b * Tn + q0 + l15) * 1024 + h * 64 + quad * 8;
            qf[0] = *(const short8*)qp;
            qf[1] = *(const short8*)(qp + 32);
        }
        floatx4 o[4];
        float lsum[4] = {0.f, 0.f, 0.f, 0.f};
#pragma unroll
        for (int i = 0; i < 4; ++i) o[i] = vzero;

        int ktiles = qt + 1;
        stage(0, 0);
        for (int kt = 0; kt < ktiles; ++kt) {
            int k0 = kt * 64;
            int bb = kt & 1;
            __syncthreads();   // tile kt staged; all waves done with other buffer

            short8 kf[4][2], vf[4][2];
#pragma unroll
            for (int f = 0; f < 4; ++f) {
                int key = f * 16 + l15;
                const char* kbase = (const char*)&ldsK[bb][0] + key * 128;
                const char* vbase = (const char*)&ldsV[bb][0] + key * 128;
#pragma unroll
                for (int ks = 0; ks < 2; ++ks) {
                    int slot = ((quad + ks * 4) ^ (key & 7)) << 4;
                    kf[f][ks] = *(const short8*)(kbase + slot);
                    vf[f][ks] = *(const short8*)(vbase + slot);
                }
            }
            if (kt + 1 < ktiles) stage(bb ^ 1, k0 + 64);   // prefetch flies during compute

            floatx4 s[4];
#pragma unroll
            for (int f = 0; f < 4; ++f) {
                s[f] = mfma16(qf[0], kf[f][0], vzero);
                s[f] = mfma16(qf[1], kf[f][1], s[f]);
            }

            u64 msk = smsk[kt];
            unsigned mlo = (unsigned)msk, mhi = (unsigned)(msk >> 32);
            int mb[4];
            mb[0] = (mlo >> l15) & 1; mb[1] = (mlo >> (l15 + 16)) & 1;
            mb[2] = (mhi >> l15) & 1; mb[3] = (mhi >> (l15 + 16)) & 1;

#pragma unroll
            for (int r = 0; r < 4; ++r) {
                int lim = q0 + quad * 4 + r - k0;   // key offsets > lim are causal-masked
                float psum = 0.f;
#pragma unroll
                for (int f = 0; f < 4; ++f) {
                    float v = (16 * f + l15 > lim || mb[f]) ? -1e10f : s[f][r];
                    float p = __builtin_amdgcn_exp2f(v - FIXEDMAX);
                    psum += p;
                    unsigned u = __float_as_uint(p) + 0x8000u;   // round-half-up bf16
                    ldsP[w][(quad * 4 + r) * 72 + f * 16 + l15] = (u16)(u >> 16);
                }
                lsum[r] += psum;
            }
            __asm__ volatile("s_waitcnt lgkmcnt(0)" ::: "memory");   // wave-local P roundtrip
            short8 pf0 = *(const short8*)((const char*)&ldsP[w][0] + l15 * 144 + quad * 16);
            short8 pf1 = *(const short8*)((const char*)&ldsP[w][0] + l15 * 144 + 64 + quad * 16);
#pragma unroll
            for (int nb = 0; nb < 4; ++nb) {
                o[nb] = mfma16(pf0, vf[nb][0], o[nb]);
                o[nb] = mfma16(pf1, vf[nb][1], o[nb]);
            }
        }
        __syncthreads();   // all waves done with buffers before next phase restages

#pragma unroll
        for (int r = 0; r < 4; ++r) {
            int qq = q0 + quad * 4 + r;
            float l = lsum[r];
#pragma unroll
            for (int off = 1; off < 16; off <<= 1) l += __shfl_xor(l, off, 64);
            bool degen = (l == 0.f);   // fully-masked row -> reference attends uniformly to ALL keys
            float linv = 1.0f / l;
#pragma unroll
            for (int nb = 0; nb < 4; ++nb) {
                int d = nb * 16 + l15;
                float val = degen ? vmean[b * 1024 + h * 64 + d] : o[nb][r] * linv;
                float pv = __shfl_xor(val, 1, 64);
                if (!(lane & 1)) {
                    unsigned pk = (unsigned)f2bf(val) | ((unsigned)f2bf(pv) << 16);
                    *(unsigned*)(Yb + (size_t)(b * Tn + qq) * 1024 + h * 64 + d) = pk;
                }
            }
        }
    }
}

extern "C" void kernel_launch(void* const* d_in, const int* in_sizes, int n_in,
                              void* d_out, int out_size, void* d_ws, size_t ws_size,
                              hipStream_t stream) {
    const float* x  = (const float*)d_in[0];
    const int* masks = (const int*)d_in[1];
    const float* Wq = (const float*)d_in[2];
    const float* bq = (const float*)d_in[3];
    const float* Wk = (const float*)d_in[4];
    const float* bk = (const float*)d_in[5];
    const float* Wv = (const float*)d_in[6];
    const float* bv = (const float*)d_in[7];
    const float* Wo = (const float*)d_in[8];
    const float2* rope = (const float2*)d_in[9];
    float* out = (float*)d_out;

    char* ws = (char*)d_ws;
    u16* xb   = (u16*)(ws);
    u16* Wqb  = (u16*)(ws + (8  << 20));
    u16* Wkb  = (u16*)(ws + (10 << 20));
    u16* Wvb  = (u16*)(ws + (12 << 20));
    u16* Wob  = (u16*)(ws + (14 << 20));
    u16* Qb   = (u16*)(ws + (16 << 20));
    u16* Kb2  = (u16*)(ws + (24 << 20));
    u16* Vt   = (u16*)(ws + (32 << 20));
    u16* Yb   = (u16*)(ws + (40 << 20));
    float* vm = (float*)(ws + (48 << 20));

    // fused f32 -> bf16 (x, Wq, Wk, Wv, Wo -> contiguous ws region)
    cvt_all_k<<<8192, 256, 0, stream>>>(x, Wq, Wk, Wv, Wo, xb);

    // fused QKV projection (+bias, rope on Q/K with QSCALE on Q, V transposed)
    gemm_qkv_k<<<dim3(16, 32, 3), 256, 0, stream>>>(xb, Wqb, Wkb, Wvb, bq, bk, bv,
                                                    Qb, Kb2, Vt, rope);
    // mean of V per (b,h,d) for degenerate fully-masked rows
    vmean_k<<<2048, 64, 0, stream>>>(Vt, vm);
    // flash attention
    flash_k<<<dim3(16, 32), 256, 0, stream>>>(Qb, Kb2, Vt, masks, vm, Yb);
    // output projection -> f32 d_out
    gemm_o_k<<<dim3(16, 64), 256, 0, stream>>>(Yb, Wob, out);
}

// Round 5
// 193.624 us; speedup vs baseline: 1.8776x; 1.0446x over previous
//
#include <hip/hip_runtime.h>

typedef short short8 __attribute__((ext_vector_type(8)));
typedef float floatx4 __attribute__((ext_vector_type(4)));
typedef unsigned short u16;
typedef unsigned long long u64;

#define Tn 2048
#define Kdim 1024
// 1/sqrt(64) * log2(e): folded into Q so flash softmax runs in exp2 domain
#define QSCALE 0.18033688011112042f
#define FIXEDMAX 20.0f   // exp2-domain logits are ~+-5; 20 is a safe fixed max

__device__ inline u16 f2bf(float x) {
    union { float f; unsigned u; } c; c.f = x;
    unsigned u = c.u;
    u += 0x7fffu + ((u >> 16) & 1u);   // round-to-nearest-even
    return (u16)(u >> 16);
}
__device__ inline float bf2f(u16 h) {
    union { unsigned u; float f; } c; c.u = ((unsigned)h) << 16;
    return c.f;
}
__device__ inline floatx4 mfma16(short8 a, short8 b, floatx4 c) {
    return __builtin_amdgcn_mfma_f32_16x16x32_bf16(a, b, c, 0, 0, 0);
}
__device__ inline void async16(const void* g, void* l) {
    __builtin_amdgcn_global_load_lds((const __attribute__((address_space(1))) void*)g,
                                     (__attribute__((address_space(3))) void*)l, 16, 0, 0);
}

// ---------------- fused f32 -> bf16 convert (x, Wq, Wk, Wv, Wo) ----------------
__global__ __launch_bounds__(256) void cvt_all_k(
    const float* __restrict__ x, const float* __restrict__ wq, const float* __restrict__ wk,
    const float* __restrict__ wv, const float* __restrict__ wo, u16* __restrict__ dst)
{
    int i = blockIdx.x * 256 + threadIdx.x;   // float4 index
    const float* s; int off;
    if (i < 1048576) { s = x; off = i; }
    else {
        int j = i - 1048576; int seg = j >> 18; off = j & 262143;
        s = (seg == 0) ? wq : (seg == 1) ? wk : (seg == 2) ? wv : wo;
    }
    float4 v = ((const float4*)s)[off];
    u64 pk = (u64)f2bf(v.x) | ((u64)f2bf(v.y) << 16) | ((u64)f2bf(v.z) << 32) | ((u64)f2bf(v.w) << 48);
    ((u64*)dst)[i] = pk;
}

// ---------------- QKV GEMM: C = A(M,K) @ W(N,K)^T + bias, 128M x 64N tile, BK=64 ----------------
__global__ __launch_bounds__(256, 5) void gemm_qkv_k(
    const u16* __restrict__ A,
    const u16* __restrict__ W0, const u16* __restrict__ W1, const u16* __restrict__ W2,
    const float* __restrict__ b0, const float* __restrict__ b1, const float* __restrict__ b2,
    u16* o0, u16* o1, u16* o2,
    const float2* __restrict__ rope)
{
    int z = blockIdx.z;
    const u16* W = (z == 0) ? W0 : (z == 1 ? W1 : W2);
    const float* bias = (z == 0) ? b0 : (z == 1 ? b1 : b2);
    u16* outp = (z == 0) ? o0 : (z == 1 ? o1 : o2);

    __shared__ __align__(16) char lds[24576];   // A [0,16K): 128 rows x 128B; W [16K,24K): 64 rows x 128B
    int tid = threadIdx.x;
    int w = tid >> 6, lane = tid & 63, quad = lane >> 4, l15 = lane & 15;
    int m0 = blockIdx.y * 128, n0 = blockIdx.x * 64;
    int wm = w * 32;

    floatx4 acc[2][4];
    floatx4 vzero = {0.f, 0.f, 0.f, 0.f};
#pragma unroll
    for (int i = 0; i < 2; ++i)
#pragma unroll
        for (int j = 0; j < 4; ++j) acc[i][j] = vzero;

    for (int k0 = 0; k0 < Kdim; k0 += 64) {
#pragma unroll
        for (int j = 0; j < 4; ++j) {
            int f = j * 256 + tid, r = f >> 3, c = (f & 7) ^ (r & 7);
            async16(A + (size_t)(m0 + r) * Kdim + k0 + c * 8, lds + j * 4096 + w * 1024);
        }
#pragma unroll
        for (int j = 0; j < 2; ++j) {
            int f = j * 256 + tid, r = f >> 3, c = (f & 7) ^ (r & 7);
            async16(W + (size_t)(n0 + r) * Kdim + k0 + c * 8, lds + 16384 + j * 4096 + w * 1024);
        }
        __syncthreads();
        short8 af[2][2];
#pragma unroll
        for (int mt = 0; mt < 2; ++mt) {
            int ra = wm + mt * 16 + l15;
            const char* pa = lds + ra * 128;
#pragma unroll
            for (int ks = 0; ks < 2; ++ks)
                af[mt][ks] = *(const short8*)(pa + (((ks * 4 + quad) ^ (ra & 7)) << 4));
        }
#pragma unroll
        for (int ks = 0; ks < 2; ++ks)
#pragma unroll
            for (int nt = 0; nt < 4; ++nt) {
                int rb = nt * 16 + l15;
                short8 bf = *(const short8*)(lds + 16384 + rb * 128 + (((ks * 4 + quad) ^ (rb & 7)) << 4));
                acc[0][nt] = mfma16(af[0][ks], bf, acc[0][nt]);
                acc[1][nt] = mfma16(af[1][ks], bf, acc[1][nt]);
            }
        __syncthreads();
    }

    int mbase = m0 + wm;
    if (z <= 1) {
        float osc = (z == 0) ? QSCALE : 1.0f;
#pragma unroll
        for (int nt = 0; nt < 4; ++nt) {
            int col = n0 + nt * 16 + l15;
            float bv = bias[col];
            int p = (col & 63) >> 1;
#pragma unroll
            for (int mt = 0; mt < 2; ++mt) {
                floatx4 a = acc[mt][nt];
#pragma unroll
                for (int r = 0; r < 4; ++r) {
                    int row = mbase + mt * 16 + quad * 4 + r;
                    float v = a[r] + bv;
                    float ov = __shfl_xor(v, 1, 64);
                    float2 cs = rope[(row & (Tn - 1)) * 32 + p];
                    float res = (cs.x * v + ((lane & 1) ? cs.y * ov : -cs.y * ov)) * osc;
                    float pres = __shfl_xor(res, 1, 64);
                    if (!(lane & 1)) {
                        unsigned pk = (unsigned)f2bf(res) | ((unsigned)f2bf(pres) << 16);
                        *(unsigned*)(outp + (size_t)row * 1024 + col) = pk;
                    }
                }
            }
        }
    } else {
#pragma unroll
        for (int nt = 0; nt < 4; ++nt) {
            int col = n0 + nt * 16 + l15;
            float bv = bias[col];
#pragma unroll
            for (int mt = 0; mt < 2; ++mt) {
                floatx4 a = acc[mt][nt];
                int row0 = mbase + mt * 16 + quad * 4;
                int bb = row0 >> 11, t0 = row0 & (Tn - 1);
                u64 pk = (u64)f2bf(a[0] + bv) | ((u64)f2bf(a[1] + bv) << 16)
                       | ((u64)f2bf(a[2] + bv) << 32) | ((u64)f2bf(a[3] + bv) << 48);
                *(u64*)(outp + (size_t)(bb * 1024 + col) * Tn + t0) = pk;
            }
        }
    }
}

// ---------------- O-projection GEMM: out = Y(M,K) @ Wo(N,K)^T, f32 out, 64x64 tile ----------------
__global__ __launch_bounds__(256, 4) void gemm_o_k(
    const u16* __restrict__ A, const u16* __restrict__ W, float* __restrict__ out)
{
    __shared__ __align__(16) char lds[16384];
    int tid = threadIdx.x;
    int w = tid >> 6, lane = tid & 63, quad = lane >> 4, l15 = lane & 15;
    int m0 = blockIdx.y * 64, n0 = blockIdx.x * 64;
    int wm = (w >> 1) * 32, wn = (w & 1) * 32;

    floatx4 acc[2][2];
    floatx4 vzero = {0.f, 0.f, 0.f, 0.f};
#pragma unroll
    for (int i = 0; i < 2; ++i)
#pragma unroll
        for (int j = 0; j < 2; ++j) acc[i][j] = vzero;

    for (int k0 = 0; k0 < Kdim; k0 += 64) {
#pragma unroll
        for (int j = 0; j < 2; ++j) {
            int f = j * 256 + tid, r = f >> 3, c = (f & 7) ^ (r & 7);
            async16(A + (size_t)(m0 + r) * Kdim + k0 + c * 8, lds + j * 4096 + w * 1024);
            async16(W + (size_t)(n0 + r) * Kdim + k0 + c * 8, lds + 8192 + j * 4096 + w * 1024);
        }
        __syncthreads();
        short8 af[2][2];
#pragma unroll
        for (int mt = 0; mt < 2; ++mt) {
            int ra = wm + mt * 16 + l15;
            const char* pa = lds + ra * 128;
#pragma unroll
            for (int ks = 0; ks < 2; ++ks)
                af[mt][ks] = *(const short8*)(pa + (((ks * 4 + quad) ^ (ra & 7)) << 4));
        }
#pragma unroll
        for (int ks = 0; ks < 2; ++ks)
#pragma unroll
            for (int nt = 0; nt < 2; ++nt) {
                int rb = wn + nt * 16 + l15;
                short8 bf = *(const short8*)(lds + 8192 + rb * 128 + (((ks * 4 + quad) ^ (rb & 7)) << 4));
                acc[0][nt] = mfma16(af[0][ks], bf, acc[0][nt]);
                acc[1][nt] = mfma16(af[1][ks], bf, acc[1][nt]);
            }
        __syncthreads();
    }

#pragma unroll
    for (int nt = 0; nt < 2; ++nt) {
        int col = n0 + wn + nt * 16 + l15;
#pragma unroll
        for (int mt = 0; mt < 2; ++mt) {
            floatx4 a = acc[mt][nt];
#pragma unroll
            for (int r = 0; r < 4; ++r) {
                int row = m0 + wm + mt * 16 + quad * 4 + r;
                out[(size_t)row * 1024 + col] = a[r];
            }
        }
    }
}

// ---------------- Vmean (for degenerate fully-masked rows) ----------------
__global__ __launch_bounds__(64) void vmean_k(const u16* __restrict__ Vt, float* __restrict__ vmean) {
    int row = blockIdx.x;
    int lane = threadIdx.x;
    const u16* p = Vt + (size_t)row * Tn;
    float s = 0.f;
    for (int i = lane * 8; i < Tn; i += 512) {
        short8 v = *(const short8*)(p + i);
#pragma unroll
        for (int j = 0; j < 8; ++j) s += bf2f((u16)v[j]);
    }
#pragma unroll
    for (int off = 1; off < 64; off <<= 1) s += __shfl_xor(s, off, 64);
    if (lane == 0) vmean[row] = s * (1.f / 2048.f);
}

// ---------------- Flash attention (fixed-max exp2 softmax) ----------------
// 1024 blocks, one 64-q tile each. XCD-clustered: bh = (bid&7)*4 + ((bid>>3)&3) so each
// XCD (round-robin bid%8) touches 4 heads -> K/V working set 2MB fits per-XCD L2.
// qt big-first within XCD. LDS exactly 40KB -> up to 4 blocks/CU.
__global__ __launch_bounds__(256) void flash_k(
    const u16* __restrict__ Qb, const u16* __restrict__ Kb, const u16* __restrict__ Vt,
    const int* __restrict__ masks, const float* __restrict__ vmean, u16* __restrict__ Yb)
{
    int bid = blockIdx.x;
    int bh = (bid & 7) * 4 + ((bid >> 3) & 3);
    int qt = 31 - (bid >> 5);           // big tiles dispatched first
    int b = bh >> 4, h = bh & 15;
    int tid = threadIdx.x, w = tid >> 6, lane = tid & 63, quad = lane >> 4, l15 = lane & 15;
    int sc = (lane & 7) ^ (lane >> 3);   // staging chunk so that LDS slot = chunk ^ (row&7)

    __shared__ __align__(16) u16 ldsK[2][64 * 64];   // row=key, 8x16B slots, swizzled (16KB)
    __shared__ __align__(16) u16 ldsV[2][64 * 64];   // row=d,   8x16B slots, swizzled (16KB)
    __shared__ __align__(16) u16 ldsP[4][16 * 64];   // per wave, 16 rows x 128B, swizzled (8KB)

    int ktiles = qt + 1;
    // mask ballots kept in registers: lane j holds ballot of key-tile j
    unsigned blo = 0, bhi = 0;
    for (int j = 0; j < ktiles; ++j) {
        u64 mk = __ballot(masks[b * Tn + j * 64 + lane] != 0);
        if (lane == j) { blo = (unsigned)mk; bhi = (unsigned)(mk >> 32); }
    }

    auto stage = [&](int bb, int k0) {
#pragma unroll
        for (int j = 0; j < 2; ++j) {
            int row = j * 32 + w * 8 + (lane >> 3);
            const u16* gk = Kb + (size_t)(b * Tn + k0 + row) * 1024 + h * 64 + sc * 8;
            async16(gk, (char*)&ldsK[bb][0] + (j * 32 + w * 8) * 128);
            const u16* gv = Vt + (size_t)(b * 1024 + h * 64 + row) * Tn + k0 + sc * 8;
            async16(gv, (char*)&ldsV[bb][0] + (j * 32 + w * 8) * 128);
        }
    };
    floatx4 vzero = {0.f, 0.f, 0.f, 0.f};

    int q0 = qt * 64 + w * 16;
    short8 qf[2];
    {
        const u16* qp = Qb + (size_t)(b * Tn + q0 + l15) * 1024 + h * 64 + quad * 8;
        qf[0] = *(const short8*)qp;
        qf[1] = *(const short8*)(qp + 32);
    }
    floatx4 o[4];
    float lsum[4] = {0.f, 0.f, 0.f, 0.f};
#pragma unroll
    for (int i = 0; i < 4; ++i) o[i] = vzero;

    stage(0, 0);
    for (int kt = 0; kt < ktiles; ++kt) {
        int k0 = kt * 64;
        int bb = kt & 1;
        __syncthreads();   // tile kt staged; all waves done with other buffer

        short8 kf[4][2], vf[4][2];
#pragma unroll
        for (int f = 0; f < 4; ++f) {
            int key = f * 16 + l15;
            const char* kbase = (const char*)&ldsK[bb][0] + key * 128;
            const char* vbase = (const char*)&ldsV[bb][0] + key * 128;
#pragma unroll
            for (int ks = 0; ks < 2; ++ks) {
                int slot = ((quad + ks * 4) ^ (key & 7)) << 4;
                kf[f][ks] = *(const short8*)(kbase + slot);
                vf[f][ks] = *(const short8*)(vbase + slot);
            }
        }
        if (kt + 1 < ktiles) stage(bb ^ 1, k0 + 64);   // prefetch flies during compute

        floatx4 s[4];
#pragma unroll
        for (int f = 0; f < 4; ++f) {
            s[f] = mfma16(qf[0], kf[f][0], vzero);
            s[f] = mfma16(qf[1], kf[f][1], s[f]);
        }

        unsigned mlo = __shfl(blo, kt, 64), mhi = __shfl(bhi, kt, 64);
        int mb[4];
        mb[0] = (mlo >> l15) & 1; mb[1] = (mlo >> (l15 + 16)) & 1;
        mb[2] = (mhi >> l15) & 1; mb[3] = (mhi >> (l15 + 16)) & 1;

        if (k0 + 63 <= q0) {
            // strictly sub-diagonal: no causal test needed
#pragma unroll
            for (int r = 0; r < 4; ++r) {
                float psum = 0.f;
#pragma unroll
                for (int f = 0; f < 4; ++f) {
                    float v = mb[f] ? -1e10f : s[f][r];
                    float p = __builtin_amdgcn_exp2f(v - FIXEDMAX);
                    psum += p;
                    unsigned u = __float_as_uint(p) + 0x8000u;
                    int row = quad * 4 + r, key = f * 16 + l15;
                    ldsP[w][0] = ldsP[w][0];   // no-op to keep array alive
                    *((u16*)((char*)&ldsP[w][0] + row * 128 +
                             ((((key >> 3) ^ (row & 7))) << 4) + (key & 7) * 2)) = (u16)(u >> 16);
                }
                lsum[r] += psum;
            }
        } else {
            // diagonal tile: causal + mask
#pragma unroll
            for (int r = 0; r < 4; ++r) {
                int lim = q0 + quad * 4 + r - k0;
                float psum = 0.f;
#pragma unroll
                for (int f = 0; f < 4; ++f) {
                    float v = (16 * f + l15 > lim || mb[f]) ? -1e10f : s[f][r];
                    float p = __builtin_amdgcn_exp2f(v - FIXEDMAX);
                    psum += p;
                    unsigned u = __float_as_uint(p) + 0x8000u;
                    int row = quad * 4 + r, key = f * 16 + l15;
                    *((u16*)((char*)&ldsP[w][0] + row * 128 +
                             ((((key >> 3) ^ (row & 7))) << 4) + (key & 7) * 2)) = (u16)(u >> 16);
                }
                lsum[r] += psum;
            }
        }
        __asm__ volatile("s_waitcnt lgkmcnt(0)" ::: "memory");   // wave-local P roundtrip
        short8 pf0 = *(const short8*)((const char*)&ldsP[w][0] + l15 * 128 + ((quad ^ (l15 & 7)) << 4));
        short8 pf1 = *(const short8*)((const char*)&ldsP[w][0] + l15 * 128 + (((quad + 4) ^ (l15 & 7)) << 4));
#pragma unroll
        for (int nb = 0; nb < 4; ++nb) {
            o[nb] = mfma16(pf0, vf[nb][0], o[nb]);
            o[nb] = mfma16(pf1, vf[nb][1], o[nb]);
        }
    }

#pragma unroll
    for (int r = 0; r < 4; ++r) {
        int qq = q0 + quad * 4 + r;
        float l = lsum[r];
#pragma unroll
        for (int off = 1; off < 16; off <<= 1) l += __shfl_xor(l, off, 64);
        bool degen = (l == 0.f);   // fully-masked row -> reference attends uniformly to ALL keys
        float linv = 1.0f / l;
#pragma unroll
        for (int nb = 0; nb < 4; ++nb) {
            int d = nb * 16 + l15;
            float val = degen ? vmean[b * 1024 + h * 64 + d] : o[nb][r] * linv;
            float pv = __shfl_xor(val, 1, 64);
            if (!(lane & 1)) {
                unsigned pk = (unsigned)f2bf(val) | ((unsigned)f2bf(pv) << 16);
                *(unsigned*)(Yb + (size_t)(b * Tn + qq) * 1024 + h * 64 + d) = pk;
            }
        }
    }
}

extern "C" void kernel_launch(void* const* d_in, const int* in_sizes, int n_in,
                              void* d_out, int out_size, void* d_ws, size_t ws_size,
                              hipStream_t stream) {
    const float* x  = (const float*)d_in[0];
    const int* masks = (const int*)d_in[1];
    const float* Wq = (const float*)d_in[2];
    const float* bq = (const float*)d_in[3];
    const float* Wk = (const float*)d_in[4];
    const float* bk = (const float*)d_in[5];
    const float* Wv = (const float*)d_in[6];
    const float* bv = (const float*)d_in[7];
    const float* Wo = (const float*)d_in[8];
    const float2* rope = (const float2*)d_in[9];
    float* out = (float*)d_out;

    char* ws = (char*)d_ws;
    u16* xb   = (u16*)(ws);
    u16* Wqb  = (u16*)(ws + (8  << 20));
    u16* Wkb  = (u16*)(ws + (10 << 20));
    u16* Wvb  = (u16*)(ws + (12 << 20));
    u16* Wob  = (u16*)(ws + (14 << 20));
    u16* Qb   = (u16*)(ws + (16 << 20));
    u16* Kb2  = (u16*)(ws + (24 << 20));
    u16* Vt   = (u16*)(ws + (32 << 20));
    u16* Yb   = (u16*)(ws + (40 << 20));
    float* vm = (float*)(ws + (48 << 20));

    // fused f32 -> bf16 (x, Wq, Wk, Wv, Wo -> contiguous ws region)
    cvt_all_k<<<8192, 256, 0, stream>>>(x, Wq, Wk, Wv, Wo, xb);

    // fused QKV projection (+bias, rope on Q/K with QSCALE on Q, V transposed)
    gemm_qkv_k<<<dim3(16, 32, 3), 256, 0, stream>>>(xb, Wqb, Wkb, Wvb, bq, bk, bv,
                                                    Qb, Kb2, Vt, rope);
    // mean of V per (b,h,d) for degenerate fully-masked rows
    vmean_k<<<2048, 64, 0, stream>>>(Vt, vm);
    // flash attention
    flash_k<<<1024, 256, 0, stream>>>(Qb, Kb2, Vt, masks, vm, Yb);
    // output projection -> f32 d_out
    gemm_o_k<<<dim3(16, 64), 256, 0, stream>>>(Yb, Wob, out);
}